// Round 3
// baseline (503.820 us; speedup 1.0000x reference)
//
#include <hip/hip_runtime.h>

#define NEG_INF (-1e9f)
#define SCALE_F 0.08838834764831845f

typedef __attribute__((ext_vector_type(8))) short short8;
typedef __attribute__((ext_vector_type(4))) float float4v;

__device__ __constant__ int cDR[8] = {1,1,0,-1,-1,-1,0,1};
__device__ __constant__ int cDC[8] = {0,1,1,1,0,-1,-1,-1};
__device__ __constant__ int cKR[8] = {2,1,-1,-2,-2,-1,1,2};
__device__ __constant__ int cKC[8] = {1,2,2,1,-1,-2,-2,-1};

__device__ __forceinline__ ushort f2bf(float f) {
  union { float f; unsigned u; } a; a.f = f;
  unsigned u = a.u;
  return (ushort)((u + 0x7FFFu + ((u >> 16) & 1u)) >> 16);
}

// truncation-pack 8 f32 -> 8 bf16 (error 2^-8, irrelevant vs threshold)
__device__ __forceinline__ short8 pack8(float4 a, float4 b) {
  union { short8 v; unsigned u[4]; } o;
  unsigned a0 = __float_as_uint(a.x), a1 = __float_as_uint(a.y);
  unsigned a2 = __float_as_uint(a.z), a3 = __float_as_uint(a.w);
  unsigned b0 = __float_as_uint(b.x), b1 = __float_as_uint(b.y);
  unsigned b2 = __float_as_uint(b.z), b3 = __float_as_uint(b.w);
  o.u[0] = (a1 & 0xFFFF0000u) | (a0 >> 16);
  o.u[1] = (a3 & 0xFFFF0000u) | (a2 >> 16);
  o.u[2] = (b1 & 0xFFFF0000u) | (b0 >> 16);
  o.u[3] = (b3 & 0xFFFF0000u) | (b2 >> 16);
  return o.v;
}

// Wsw layout (LINEAR): [kc][row][kin] bf16, chunk-major (36864 B per chunk).
// row 0..255: 0-127 Wq cols, 128-255 Wk cols. (Promo handled by apol_promo.)
__global__ void wconv_kernel(const float* __restrict__ Wq,
                             const float* __restrict__ Wk,
                             ushort* __restrict__ Wsw) {
  int row = blockIdx.x;  // 0..255
  for (int k = threadIdx.x; k < 1024; k += 256) {
    float v = (row < 128) ? Wq[k * 128 + row] : Wk[k * 128 + (row - 128)];
    int kc = k >> 6, kin = k & 63;
    Wsw[(size_t)kc * 18432 + row * 64 + kin] = f2bf(v);
  }
}

// promo logits: out[b, 48+r, 64+c] = x[b, 48+r, :] . Wu[:, c] + bu[c]
// 72 outputs/elem, f32 dot. Wu/x-rows are L2/L3 resident; ~3 us total.
__global__ void apol_promo(const float* __restrict__ x,
                           const float* __restrict__ Wu,
                           const float* __restrict__ bu,
                           float* __restrict__ out) {
  int b = blockIdx.x;
  int t = threadIdx.x;
  if (t >= 72) return;
  int r = t / 9, c = t - r * 9;
  const float* xr = x + (size_t)b * 65536 + (48 + r) * 1024;
  float s = 0.f;
  for (int d = 0; d < 1024; d += 4) {
    float4 xv = *(const float4*)(xr + d);
    s += xv.x * Wu[d * 9 + c] + xv.y * Wu[(d + 1) * 9 + c] +
         xv.z * Wu[(d + 2) * 9 + c] + xv.w * Wu[(d + 3) * 9 + c];
  }
  out[(size_t)b * 4672 + (48 + r) * 73 + 64 + c] = s + bu[c];
}

// Depth-1 software pipeline, all staging in registers:
//   chunk k: issue W(k+1)->regs (ping/pong) + x(k+1)->regs; MFMAs consume
//   W(k) regs + x(k) bf16 LDS tile; pack+ds_write x(k+1); ONE barrier.
// The barrier's vmcnt(0) drain is harmless: prefetch loads had the whole
// compute phase to land. Compute phase itself waits only on lgkm (ds_read).
__global__ __launch_bounds__(256, 3)
void apol_main(const float* __restrict__ x,
               const float* __restrict__ bq,
               const float* __restrict__ bk,
               const ushort* __restrict__ Wsw,
               float* __restrict__ out) {
  // LDS union:
  //  phase1: xs bf16[2][64][64] double-buffer (2 x 8192 B)         = 16384 B
  //  phase2: qs[64][132] + ks[64][132] bf16                        = 33792 B
  //  phase3: Sl f32[64][65]                                        = 16640 B
  __shared__ __align__(16) char smem[33792];
  char*   xs0 = smem;
  char*   xs1 = smem + 8192;
  ushort* qs  = (ushort*)smem;
  ushort* ks  = (ushort*)(smem + 16896);
  float*  Sl  = (float*)smem;

  const int tid = threadIdx.x;
  const int w = tid >> 6, lane = tid & 63;
  const int l15 = lane & 15, qd = lane >> 4;
  const char* xb = (const char*)(x + (size_t)blockIdx.x * 65536);
  const char* WsB = (const char*)Wsw;

  // x stage: lane handles row w*16+(lane>>2), 16 consecutive f32 at col
  // (lane&3)*16 -> 2 bf16 granules of 16B.
  const int srow = w * 16 + (lane >> 2);
  const int scol4 = lane & 3;
  const char* xsrc = xb + srow * 4096 + scol4 * 64;  // + kc*256 per chunk
  // bf16 tile row stride 128B, 8 granules/row, XOR-swizzled by row&7.
  const int wr0 = srow * 128 + (((scol4 * 2 + 0) ^ (srow & 7)) * 16);
  const int wr1 = srow * 128 + (((scol4 * 2 + 1) ^ (srow & 7)) * 16);

  // A-frag read: row=mt*16+l15, granule kk*4+qd, same swizzle key (row&7=l15&7)
  const int arow = l15 * 128;
  const int aoff0 = (((0 * 4 + qd) ^ (l15 & 7)) * 16);
  const int aoff1 = (((1 * 4 + qd) ^ (l15 & 7)) * 16);

  // W global voffset: row=(w*64+nt*16+l15), byte = row*128 + (kk*4+qd)*16.
  const int wvo = (w * 64 + l15) * 128 + qd * 16;

  float4v acc[4][4];
  #pragma unroll
  for (int i = 0; i < 4; ++i)
    #pragma unroll
    for (int j = 0; j < 4; ++j)
      acc[i][j] = (float4v){0.f, 0.f, 0.f, 0.f};

  short8 bwA[2][4], bwB[2][4];   // W ping/pong register sets
  float4 gx0, gx1, gx2, gx3;     // x prefetch (loaded+consumed within a body)

  // prologue: W(0) -> bwA, x(0) -> xs0
  #pragma unroll
  for (int kk = 0; kk < 2; ++kk)
    #pragma unroll
    for (int nt = 0; nt < 4; ++nt)
      bwA[kk][nt] = *(const short8*)(WsB + wvo + nt * 2048 + kk * 64);
  {
    gx0 = *(const float4*)(xsrc);
    gx1 = *(const float4*)(xsrc + 16);
    gx2 = *(const float4*)(xsrc + 32);
    gx3 = *(const float4*)(xsrc + 48);
    *(short8*)(xs0 + wr0) = pack8(gx0, gx1);
    *(short8*)(xs0 + wr1) = pack8(gx2, gx3);
  }
  __syncthreads();

#define CHUNK_BODY(KC, XCUR, XNXT, BWC, BWN)                                   \
  {                                                                            \
    const bool pf = (KC) < 15;                                                 \
    if (pf) {                                                                  \
      const char* wpn = WsB + (size_t)((KC) + 1) * 36864;                      \
      _Pragma("unroll")                                                        \
      for (int kk = 0; kk < 2; ++kk)                                           \
        _Pragma("unroll")                                                      \
        for (int nt = 0; nt < 4; ++nt)                                         \
          BWN[kk][nt] = *(const short8*)(wpn + wvo + nt * 2048 + kk * 64);     \
      const char* s = xsrc + ((KC) + 1) * 256;                                 \
      gx0 = *(const float4*)(s);                                               \
      gx1 = *(const float4*)(s + 16);                                          \
      gx2 = *(const float4*)(s + 32);                                          \
      gx3 = *(const float4*)(s + 48);                                          \
    }                                                                          \
    _Pragma("unroll")                                                          \
    for (int mt = 0; mt < 4; ++mt) {                                           \
      short8 af0 = *(const short8*)((XCUR) + mt * 2048 + arow + aoff0);        \
      _Pragma("unroll")                                                        \
      for (int nt = 0; nt < 4; ++nt)                                           \
        acc[mt][nt] = __builtin_amdgcn_mfma_f32_16x16x32_bf16(                 \
            af0, BWC[0][nt], acc[mt][nt], 0, 0, 0);                            \
    }                                                                          \
    _Pragma("unroll")                                                          \
    for (int mt = 0; mt < 4; ++mt) {                                           \
      short8 af1 = *(const short8*)((XCUR) + mt * 2048 + arow + aoff1);        \
      _Pragma("unroll")                                                        \
      for (int nt = 0; nt < 4; ++nt)                                           \
        acc[mt][nt] = __builtin_amdgcn_mfma_f32_16x16x32_bf16(                 \
            af1, BWC[1][nt], acc[mt][nt], 0, 0, 0);                            \
    }                                                                          \
    if (pf) {                                                                  \
      *(short8*)((XNXT) + wr0) = pack8(gx0, gx1);                              \
      *(short8*)((XNXT) + wr1) = pack8(gx2, gx3);                              \
    }                                                                          \
    __syncthreads();                                                           \
  }

  // ---------------- GEMM1: 16 chunks of BK=64, pipelined ----------------
  #pragma unroll 1
  for (int kc = 0; kc < 16; kc += 2) {
    CHUNK_BODY(kc, xs0, xs1, bwA, bwB)
    CHUNK_BODY(kc + 1, xs1, xs0, bwB, bwA)
  }
#undef CHUNK_BODY

  float* outb = out + (size_t)blockIdx.x * 4672;

  // ---------------- epilogue: acc -> qs/ks (bias, scale) ----------------
  #pragma unroll
  for (int nt = 0; nt < 4; ++nt) {
    int C = w * 64 + nt * 16 + l15;
    bool isq = (C < 128);
    int p = isq ? C : (C - 128);
    float bias = isq ? bq[p] : bk[p];
    ushort* dstb = isq ? qs : ks;
    #pragma unroll
    for (int mt = 0; mt < 4; ++mt)
      #pragma unroll
      for (int r = 0; r < 4; ++r) {
        int row = mt * 16 + qd * 4 + r;
        float v = acc[mt][nt][r] + bias;
        if (isq) v *= SCALE_F;
        dstb[row * 132 + p] = f2bf(v);
      }
  }
  __syncthreads();

  // ---------------- GEMM2: S = q' @ k'^T (64x64), K=128 ----------------
  float4v acc2[4];
  #pragma unroll
  for (int nt = 0; nt < 4; ++nt) acc2[nt] = (float4v){0.f, 0.f, 0.f, 0.f};
  #pragma unroll
  for (int kp = 0; kp < 4; ++kp) {
    int kb = kp * 32 + qd * 8;
    short8 a2 = *(const short8*)((const char*)&qs[(w * 16 + l15) * 132 + kb]);
    #pragma unroll
    for (int nt = 0; nt < 4; ++nt) {
      short8 b2 = *(const short8*)((const char*)&ks[(nt * 16 + l15) * 132 + kb]);
      acc2[nt] = __builtin_amdgcn_mfma_f32_16x16x32_bf16(a2, b2, acc2[nt], 0, 0, 0);
    }
  }
  __syncthreads();
  #pragma unroll
  for (int nt = 0; nt < 4; ++nt)
    #pragma unroll
    for (int r = 0; r < 4; ++r)
      Sl[(w * 16 + qd * 4 + r) * 65 + nt * 16 + l15] = acc2[nt][r];
  __syncthreads();

  // ---------------- gather + masks + store ----------------
  for (int idx = tid; idx < 4672; idx += 256) {
    int f = idx / 73;
    int j = idx - f * 73;
    float val;
    if (j < 64) {
      int rr = f >> 3, cc = f & 7;
      int nr, nc;
      if (j < 56) {
        int d = j / 7;
        int dist = j - d * 7 + 1;
        nr = rr + cDR[d] * dist;
        nc = cc + cDC[d] * dist;
      } else {
        nr = rr + cKR[j - 56];
        nc = cc + cKC[j - 56];
      }
      val = (nr >= 0 && nr < 8 && nc >= 0 && nc < 8) ? Sl[f * 65 + nr * 8 + nc]
                                                     : NEG_INF;
    } else {
      if (f >= 48 && f < 56) continue;  // promo slots written by apol_promo
      val = NEG_INF;
    }
    outb[idx] = val;
  }
}

extern "C" void kernel_launch(void* const* d_in, const int* in_sizes, int n_in,
                              void* d_out, int out_size, void* d_ws, size_t ws_size,
                              hipStream_t stream) {
  const float* x  = (const float*)d_in[0];
  const float* Wq = (const float*)d_in[1];
  const float* bq = (const float*)d_in[2];
  const float* Wk = (const float*)d_in[3];
  const float* bk = (const float*)d_in[4];
  const float* Wu = (const float*)d_in[5];
  const float* bu = (const float*)d_in[6];
  float* out = (float*)d_out;
  ushort* Wsw = (ushort*)d_ws;  // 16*18432 bf16 = 576 KB (rows 256+ unused)

  const int B = in_sizes[0] / 65536;

  wconv_kernel<<<256, 256, 0, stream>>>(Wq, Wk, Wsw);
  apol_promo<<<B, 128, 0, stream>>>(x, Wu, bu, out);
  apol_main<<<B, 256, 0, stream>>>(x, bq, bk, Wsw, out);
}

// Round 4
// 447.750 us; speedup vs baseline: 1.1252x; 1.1252x over previous
//
#include <hip/hip_runtime.h>

#define NEG_INF (-1e9f)
#define SCALE_F 0.08838834764831845f

typedef __attribute__((ext_vector_type(8))) short short8;
typedef __attribute__((ext_vector_type(4))) float float4v;

__device__ __constant__ int cDR[8] = {1,1,0,-1,-1,-1,0,1};
__device__ __constant__ int cDC[8] = {0,1,1,1,0,-1,-1,-1};
__device__ __constant__ int cKR[8] = {2,1,-1,-2,-2,-1,1,2};
__device__ __constant__ int cKC[8] = {1,2,2,1,-1,-2,-2,-1};

__device__ __forceinline__ ushort f2bf(float f) {
  union { float f; unsigned u; } a; a.f = f;
  unsigned u = a.u;
  return (ushort)((u + 0x7FFFu + ((u >> 16) & 1u)) >> 16);
}

// truncation-pack 8 f32 -> 8 bf16 (error 2^-8, irrelevant vs threshold)
__device__ __forceinline__ short8 pack8(float4 a, float4 b) {
  union { short8 v; unsigned u[4]; } o;
  unsigned a0 = __float_as_uint(a.x), a1 = __float_as_uint(a.y);
  unsigned a2 = __float_as_uint(a.z), a3 = __float_as_uint(a.w);
  unsigned b0 = __float_as_uint(b.x), b1 = __float_as_uint(b.y);
  unsigned b2 = __float_as_uint(b.z), b3 = __float_as_uint(b.w);
  o.u[0] = (a1 & 0xFFFF0000u) | (a0 >> 16);
  o.u[1] = (a3 & 0xFFFF0000u) | (a2 >> 16);
  o.u[2] = (b1 & 0xFFFF0000u) | (b0 >> 16);
  o.u[3] = (b3 & 0xFFFF0000u) | (b2 >> 16);
  return o.v;
}

// Wsw layout (LINEAR): [kc][row][kin] bf16, chunk-major (36864 B per chunk).
// row 0..287: 0-127 Wq cols, 128-255 Wk cols, 256-264 Wu cols, 265-287 zero.
// Consumed directly from L2 (576 KB, XCD-resident) — never staged to LDS.
__global__ void wconv_kernel(const float* __restrict__ Wq,
                             const float* __restrict__ Wk,
                             const float* __restrict__ Wu,
                             ushort* __restrict__ Wsw) {
  int row = blockIdx.x;  // 0..287
  for (int k = threadIdx.x; k < 1024; k += 256) {
    float v;
    if (row < 128)      v = Wq[k * 128 + row];
    else if (row < 256) v = Wk[k * 128 + (row - 128)];
    else if (row < 265) v = Wu[k * 9 + (row - 256)];
    else                v = 0.f;
    int kc = k >> 6, kin = k & 63;
    Wsw[(size_t)kc * 18432 + row * 64 + kin] = f2bf(v);
  }
}

// Structure: 2 halves of K. Per half: bulk-stage x[64][512] f32 -> bf16 LDS
// (coalesced 2KB/wave bursts, deep MLP), one barrier, then a BARRIER-FREE
// 8-chunk K-loop: A-frags from swizzled LDS, B-frags per-wave from L2.
// No per-chunk HBM latency exposure; TLP (8 waves/CU) hides L2 W-loads.
__global__ __launch_bounds__(256, 2)
void apol_main(const float* __restrict__ x,
               const float* __restrict__ bq,
               const float* __restrict__ bk,
               const float* __restrict__ bu,
               const ushort* __restrict__ Wsw,
               float* __restrict__ out) {
  // LDS union:
  //  phase1: xs bf16[64][512] (one K-half, swizzled)               = 65536 B
  //  phase2: qs[64][132] + ks[64][132] bf16                        = 33792 B
  //  phase3: Sl f32[64][65]                                        = 16640 B
  __shared__ __align__(16) char smem[65536];
  char*   xs  = smem;
  ushort* qs  = (ushort*)smem;
  ushort* ks  = (ushort*)(smem + 16896);
  float*  Sl  = (float*)smem;

  const int tid = threadIdx.x;
  const int w = tid >> 6, lane = tid & 63;
  const int l15 = lane & 15, qd = lane >> 4;
  const char* xb = (const char*)(x + (size_t)blockIdx.x * 65536);
  const char* WsB = (const char*)Wsw;

  // A-frag read: row=mt*16+l15 (stride 1024B), granule (kc8*8+kk*4+qd)
  // XOR-swizzled by row&7 (= l15&7).
  const int arow = l15 * 1024;
  const int axor = l15 & 7;

  // W global voffsets: row=(w*64+nt*16+l15), byte = row*128 + (kk*4+qd)*16.
  const int wvo = (w * 64 + l15) * 128 + qd * 16;
  const int uvo = (256 + l15) * 128 + qd * 16;

  float4v acc[4][4];
  #pragma unroll
  for (int i = 0; i < 4; ++i)
    #pragma unroll
    for (int j = 0; j < 4; ++j)
      acc[i][j] = (float4v){0.f, 0.f, 0.f, 0.f};
  float4v aup = (float4v){0.f, 0.f, 0.f, 0.f};

  // ---------------- GEMM1: 2 halves x 8 chunks of BK=64 ----------------
  for (int h = 0; h < 2; ++h) {
    if (h) __syncthreads();  // all reads of previous half done before overwrite
    // bulk stage: iter j stages row j*4+w; wave reads 2KB contiguous
    // (lane*32), packs to bf16, one swizzled ds_write_b128 per lane.
    #pragma unroll 8
    for (int j = 0; j < 16; ++j) {
      int row = j * 4 + w;
      const char* s = xb + row * 4096 + h * 2048 + lane * 32;
      float4 g0 = *(const float4*)(s);
      float4 g1 = *(const float4*)(s + 16);
      *(short8*)(xs + row * 1024 + ((lane ^ (row & 7)) * 16)) = pack8(g0, g1);
    }
    __syncthreads();

    const char* wh = WsB + (size_t)h * 8 * 36864;
    #pragma unroll 2
    for (int kc8 = 0; kc8 < 8; ++kc8) {
      const char* wp = wh + kc8 * 36864;
      #pragma unroll
      for (int kk = 0; kk < 2; ++kk) {
        short8 bf[4];
        #pragma unroll
        for (int nt = 0; nt < 4; ++nt)
          bf[nt] = *(const short8*)(wp + wvo + nt * 2048 + kk * 64);
        short8 ub;
        if (w == 3) ub = *(const short8*)(wp + uvo + kk * 64);
        #pragma unroll
        for (int mt = 0; mt < 4; ++mt) {
          short8 af = *(const short8*)(
              xs + mt * 16384 + arow + (((kc8 * 8 + kk * 4 + qd) ^ axor) * 16));
          #pragma unroll
          for (int nt = 0; nt < 4; ++nt)
            acc[mt][nt] = __builtin_amdgcn_mfma_f32_16x16x32_bf16(
                af, bf[nt], acc[mt][nt], 0, 0, 0);
          if (w == 3 && mt == 3)
            aup = __builtin_amdgcn_mfma_f32_16x16x32_bf16(af, ub, aup, 0, 0, 0);
        }
      }
    }
  }
  __syncthreads();  // xs reads complete; region is now free for qs/ks

  float* outb = out + (size_t)blockIdx.x * 4672;

  // promo writes: wave 3, C rows 0..7 <-> x rows 48..55, cols 0..8
  if (w == 3 && qd < 2 && l15 < 9) {
    float bias = bu[l15];
    #pragma unroll
    for (int r = 0; r < 4; ++r) {
      int f = 48 + qd * 4 + r;
      outb[f * 73 + 64 + l15] = aup[r] + bias;
    }
  }

  // ---------------- epilogue: acc -> qs/ks (bias, scale) ----------------
  #pragma unroll
  for (int nt = 0; nt < 4; ++nt) {
    int C = w * 64 + nt * 16 + l15;
    bool isq = (C < 128);
    int p = isq ? C : (C - 128);
    float bias = isq ? bq[p] : bk[p];
    ushort* dstb = isq ? qs : ks;
    #pragma unroll
    for (int mt = 0; mt < 4; ++mt)
      #pragma unroll
      for (int r = 0; r < 4; ++r) {
        int row = mt * 16 + qd * 4 + r;
        float v = acc[mt][nt][r] + bias;
        if (isq) v *= SCALE_F;
        dstb[row * 132 + p] = f2bf(v);
      }
  }
  __syncthreads();

  // ---------------- GEMM2: S = q' @ k'^T (64x64), K=128 ----------------
  float4v acc2[4];
  #pragma unroll
  for (int nt = 0; nt < 4; ++nt) acc2[nt] = (float4v){0.f, 0.f, 0.f, 0.f};
  #pragma unroll
  for (int kp = 0; kp < 4; ++kp) {
    int kb = kp * 32 + qd * 8;
    short8 a2 = *(const short8*)((const char*)&qs[(w * 16 + l15) * 132 + kb]);
    #pragma unroll
    for (int nt = 0; nt < 4; ++nt) {
      short8 b2 = *(const short8*)((const char*)&ks[(nt * 16 + l15) * 132 + kb]);
      acc2[nt] = __builtin_amdgcn_mfma_f32_16x16x32_bf16(a2, b2, acc2[nt], 0, 0, 0);
    }
  }
  __syncthreads();
  #pragma unroll
  for (int nt = 0; nt < 4; ++nt)
    #pragma unroll
    for (int r = 0; r < 4; ++r)
      Sl[(w * 16 + qd * 4 + r) * 65 + nt * 16 + l15] = acc2[nt][r];
  __syncthreads();

  // ---------------- gather + masks + store ----------------
  for (int idx = tid; idx < 4672; idx += 256) {
    int f = idx / 73;
    int j = idx - f * 73;
    float val;
    if (j < 64) {
      int rr = f >> 3, cc = f & 7;
      int nr, nc;
      if (j < 56) {
        int d = j / 7;
        int dist = j - d * 7 + 1;
        nr = rr + cDR[d] * dist;
        nc = cc + cDC[d] * dist;
      } else {
        nr = rr + cKR[j - 56];
        nc = cc + cKC[j - 56];
      }
      val = (nr >= 0 && nr < 8 && nc >= 0 && nc < 8) ? Sl[f * 65 + nr * 8 + nc]
                                                     : NEG_INF;
    } else {
      if (f >= 48 && f < 56) continue;  // promo slots written from aup
      val = NEG_INF;
    }
    outb[idx] = val;
  }
}

extern "C" void kernel_launch(void* const* d_in, const int* in_sizes, int n_in,
                              void* d_out, int out_size, void* d_ws, size_t ws_size,
                              hipStream_t stream) {
  const float* x  = (const float*)d_in[0];
  const float* Wq = (const float*)d_in[1];
  const float* bq = (const float*)d_in[2];
  const float* Wk = (const float*)d_in[3];
  const float* bk = (const float*)d_in[4];
  const float* Wu = (const float*)d_in[5];
  const float* bu = (const float*)d_in[6];
  float* out = (float*)d_out;
  ushort* Wsw = (ushort*)d_ws;  // 16*18432 bf16 = 576 KB

  const int B = in_sizes[0] / 65536;

  wconv_kernel<<<288, 256, 0, stream>>>(Wq, Wk, Wu, Wsw);
  apol_main<<<B, 256, 0, stream>>>(x, bq, bk, bu, Wsw, out);
}

// Round 5
// 441.778 us; speedup vs baseline: 1.1404x; 1.0135x over previous
//
#include <hip/hip_runtime.h>

#define NEG_INF (-1e9f)
#define SCALE_F 0.08838834764831845f

typedef __attribute__((ext_vector_type(8))) short short8;
typedef __attribute__((ext_vector_type(4))) float float4v;

__device__ __constant__ int cDR[8] = {1,1,0,-1,-1,-1,0,1};
__device__ __constant__ int cDC[8] = {0,1,1,1,0,-1,-1,-1};
__device__ __constant__ int cKR[8] = {2,1,-1,-2,-2,-1,1,2};
__device__ __constant__ int cKC[8] = {1,2,2,1,-1,-2,-2,-1};

__device__ __forceinline__ ushort f2bf(float f) {
  union { float f; unsigned u; } a; a.f = f;
  unsigned u = a.u;
  return (ushort)((u + 0x7FFFu + ((u >> 16) & 1u)) >> 16);
}

// async 16B/lane copy: global -> LDS. ldsbase must be wave-uniform; lane i
// receives bytes [i*16, i*16+16). Global source IS per-lane.
__device__ __forceinline__ void glds16(const void* g, void* l) {
  __builtin_amdgcn_global_load_lds(
      (const __attribute__((address_space(1))) unsigned int*)g,
      (__attribute__((address_space(3))) unsigned int*)l, 16, 0, 0);
}

// truncation-pack 8 f32 -> 8 bf16 (error 2^-8, irrelevant vs threshold)
__device__ __forceinline__ short8 pack8(float4 a, float4 b) {
  union { short8 v; unsigned u[4]; } o;
  unsigned a0 = __float_as_uint(a.x), a1 = __float_as_uint(a.y);
  unsigned a2 = __float_as_uint(a.z), a3 = __float_as_uint(a.w);
  unsigned b0 = __float_as_uint(b.x), b1 = __float_as_uint(b.y);
  unsigned b2 = __float_as_uint(b.z), b3 = __float_as_uint(b.w);
  o.u[0] = (a1 & 0xFFFF0000u) | (a0 >> 16);
  o.u[1] = (a3 & 0xFFFF0000u) | (a2 >> 16);
  o.u[2] = (b1 & 0xFFFF0000u) | (b0 >> 16);
  o.u[3] = (b3 & 0xFFFF0000u) | (b2 >> 16);
  return o.v;
}

// Wsw layout: [kc][row][sseg*8+j] bf16, chunk-major (18432 elems/chunk),
// row 0..287: 0-127 Wq cols, 128-255 Wk cols, 256-264 Wu cols, 265-287 zero.
// XOR swizzle: position sseg holds original k-seg (sseg ^ (row&7)); 16B
// granules stay contiguous so global_load_lds copies are linear.
__global__ void wconv_kernel(const float* __restrict__ Wq,
                             const float* __restrict__ Wk,
                             const float* __restrict__ Wu,
                             ushort* __restrict__ Wsw) {
  int row = blockIdx.x;  // 0..287
  for (int k = threadIdx.x; k < 1024; k += 256) {
    float v;
    if (row < 128)      v = Wq[k * 128 + row];
    else if (row < 256) v = Wk[k * 128 + (row - 128)];
    else if (row < 265) v = Wu[k * 9 + (row - 256)];
    else                v = 0.f;
    int kc = k >> 6, kin = k & 63, seg = kin >> 3, j = kin & 7;
    int sseg = seg ^ (row & 7);
    Wsw[(size_t)kc * 18432 + row * 64 + sseg * 8 + j] = f2bf(v);
  }
}

// R0 mechanics (glds16 for x AND W) + DOUBLE-BUFFERED DMA: chunk k+1's
// global_load_lds issue at the top of compute(k), so the per-chunk
// vmcnt(0)+barrier drain finds them already landed (m97 structure).
// 512 threads / 8 waves (2M x 4N wave grid) halve per-wave serial work.
// LDS 104KB -> 1 block/CU, 8 waves.
__global__ __launch_bounds__(512, 1)
void apol_main(const float* __restrict__ x,
               const float* __restrict__ bq,
               const float* __restrict__ bk,
               const float* __restrict__ bu,
               const ushort* __restrict__ Wsw,
               float* __restrict__ out) {
  // LDS union:
  //  phase1: xs f32[2][64][64] (2x16384) + wt bf16[2][288][64] (2x36864)
  //          = 106496 B
  //  phase2: qs[64][132] + ks[64][132] bf16 = 33792 B
  //  phase3: Sl f32[64][65] = 16640 B
  __shared__ __align__(16) char smem[106496];
  char*   xs0 = smem;
  char*   xs1 = smem + 16384;
  char*   wt0 = smem + 32768;
  char*   wt1 = smem + 69632;
  ushort* qs  = (ushort*)smem;
  ushort* ks  = (ushort*)(smem + 16896);
  float*  Sl  = (float*)smem;

  const int tid = threadIdx.x;
  const int wv = tid >> 6, lane = tid & 63;
  const int l15 = lane & 15, qd = lane >> 4;
  const int wr = wv >> 2, wc = wv & 3;   // wave grid: 2 M-rows x 4 N-cols
  const char* xb = (const char*)(x + (size_t)blockIdx.x * 65536);
  const char* WsB = (const char*)Wsw;

  const int xsrow = lane >> 4;   // subrow within a 4-row stage slot
  const int xgran = lane & 15;   // 16B granule within row

  // A-frag (f32 x) read addrs: row = wr*32+mt*16+l15 (row&7 == l15&7),
  // granule (kk*8+qd*2+h) XOR-swizzled.
  int arowb[2];
  #pragma unroll
  for (int mt = 0; mt < 2; ++mt) arowb[mt] = (wr * 32 + mt * 16 + l15) * 256;
  int agr[2][2];
  #pragma unroll
  for (int kk = 0; kk < 2; ++kk)
    #pragma unroll
    for (int h = 0; h < 2; ++h)
      agr[kk][h] = (((kk * 8 + qd * 2 + h) ^ (l15 & 7)) * 16);

  // B-frag (bf16 W) read addrs: row = wc*64+nt*16+l15, seg kk*4+qd swizzled.
  int brow[4];
  #pragma unroll
  for (int nt = 0; nt < 4; ++nt) brow[nt] = (wc * 64 + nt * 16 + l15) * 128;
  const int urow = (256 + l15) * 128;
  int bgr[2];
  #pragma unroll
  for (int kk = 0; kk < 2; ++kk)
    bgr[kk] = (((kk * 4 + qd) ^ (l15 & 7)) * 16);

  float4v acc[2][4];
  #pragma unroll
  for (int i = 0; i < 2; ++i)
    #pragma unroll
    for (int j = 0; j < 4; ++j)
      acc[i][j] = (float4v){0.f, 0.f, 0.f, 0.f};
  float4v aup = (float4v){0.f, 0.f, 0.f, 0.f};

  // stage one chunk: 52 x 1KB wave-slots (x: 0..15, W: 16..51) over 8 waves.
  // x slot s covers rows s*4..s*4+3; source granule pre-swizzled so linear
  // LDS holds position j = srcgranule ^ (row&7).
#define STAGE(KC, XD, WD)                                                      \
  {                                                                            \
    _Pragma("unroll")                                                          \
    for (int c = 0; c < 7; ++c) {                                              \
      int slot = c * 8 + wv;                                                   \
      if (slot < 16) {                                                         \
        int r = slot * 4 + xsrow;                                              \
        glds16(xb + r * 4096 + (KC) * 256 + ((xgran ^ (r & 7)) * 16),          \
               (XD) + slot * 1024);                                            \
      } else if (slot < 52) {                                                  \
        glds16(WsB + (size_t)(KC) * 36864 + (slot - 16) * 1024 + lane * 16,    \
               (WD) + (slot - 16) * 1024);                                     \
      }                                                                        \
    }                                                                          \
  }

#define COMPUTE(XC, WC)                                                        \
  {                                                                            \
    _Pragma("unroll")                                                          \
    for (int kk = 0; kk < 2; ++kk) {                                           \
      short8 bf[4];                                                            \
      _Pragma("unroll")                                                        \
      for (int nt = 0; nt < 4; ++nt)                                           \
        bf[nt] = *(const short8*)((WC) + brow[nt] + bgr[kk]);                  \
      short8 ub;                                                               \
      if (wv == 7) ub = *(const short8*)((WC) + urow + bgr[kk]);               \
      _Pragma("unroll")                                                        \
      for (int mt = 0; mt < 2; ++mt) {                                         \
        float4 g0 = *(const float4*)((XC) + arowb[mt] + agr[kk][0]);           \
        float4 g1 = *(const float4*)((XC) + arowb[mt] + agr[kk][1]);           \
        short8 af = pack8(g0, g1);                                             \
        _Pragma("unroll")                                                      \
        for (int nt = 0; nt < 4; ++nt)                                         \
          acc[mt][nt] = __builtin_amdgcn_mfma_f32_16x16x32_bf16(               \
              af, bf[nt], acc[mt][nt], 0, 0, 0);                               \
        if (wv == 7 && mt == 1)                                                \
          aup = __builtin_amdgcn_mfma_f32_16x16x32_bf16(af, ub, aup, 0, 0, 0); \
      }                                                                        \
    }                                                                          \
  }

  // ---------------- GEMM1: 16 chunks of BK=64, DMA double-buffered --------
  STAGE(0, xs0, wt0);
  __syncthreads();
  #pragma unroll 1
  for (int kc = 0; kc < 16; kc += 2) {
    STAGE(kc + 1, xs1, wt1);       // issue BEFORE compute: latency hidden
    COMPUTE(xs0, wt0);
    __syncthreads();               // drains mostly-landed DMAs
    if (kc < 14) STAGE(kc + 2, xs0, wt0);
    COMPUTE(xs1, wt1);
    __syncthreads();
  }
#undef STAGE
#undef COMPUTE

  float* outb = out + (size_t)blockIdx.x * 4672;

  // promo writes: wave 7 (rows 48-63), C rows qd*4+r <-> x rows 48+qd*4+r
  if (wv == 7 && qd < 2 && l15 < 9) {
    float bias = bu[l15];
    #pragma unroll
    for (int r = 0; r < 4; ++r) {
      int f = 48 + qd * 4 + r;
      outb[f * 73 + 64 + l15] = aup[r] + bias;
    }
  }

  // ---------------- epilogue: acc -> qs/ks (bias, scale) ----------------
  #pragma unroll
  for (int nt = 0; nt < 4; ++nt) {
    int C = wc * 64 + nt * 16 + l15;
    bool isq = (C < 128);
    int p = isq ? C : (C - 128);
    float bias = isq ? bq[p] : bk[p];
    ushort* dstb = isq ? qs : ks;
    #pragma unroll
    for (int mt = 0; mt < 2; ++mt)
      #pragma unroll
      for (int r = 0; r < 4; ++r) {
        int row = wr * 32 + mt * 16 + qd * 4 + r;
        float v = acc[mt][nt][r] + bias;
        if (isq) v *= SCALE_F;
        dstb[row * 132 + p] = f2bf(v);
      }
  }
  __syncthreads();

  // ---------------- GEMM2: S = q' @ k'^T (64x64), K=128 ----------------
  // wave wv: rows (wv>>1)*16, cols (wv&1)*32 (2 nt tiles)
  const int r16 = wv >> 1, c32 = wv & 1;
  float4v acc2[2];
  acc2[0] = (float4v){0.f, 0.f, 0.f, 0.f};
  acc2[1] = (float4v){0.f, 0.f, 0.f, 0.f};
  #pragma unroll
  for (int kp = 0; kp < 4; ++kp) {
    int kb = kp * 32 + qd * 8;
    short8 a2 = *(const short8*)((const char*)&qs[(r16 * 16 + l15) * 132 + kb]);
    #pragma unroll
    for (int nt = 0; nt < 2; ++nt) {
      short8 b2 = *(const short8*)(
          (const char*)&ks[((c32 * 2 + nt) * 16 + l15) * 132 + kb]);
      acc2[nt] = __builtin_amdgcn_mfma_f32_16x16x32_bf16(a2, b2, acc2[nt], 0, 0, 0);
    }
  }
  __syncthreads();
  #pragma unroll
  for (int nt = 0; nt < 2; ++nt)
    #pragma unroll
    for (int r = 0; r < 4; ++r)
      Sl[(r16 * 16 + qd * 4 + r) * 65 + (c32 * 2 + nt) * 16 + l15] = acc2[nt][r];
  __syncthreads();

  // ---------------- gather + masks + store ----------------
  for (int idx = tid; idx < 4672; idx += 512) {
    int f = idx / 73;
    int j = idx - f * 73;
    float val;
    if (j < 64) {
      int rr = f >> 3, cc = f & 7;
      int nr, nc;
      if (j < 56) {
        int d = j / 7;
        int dist = j - d * 7 + 1;
        nr = rr + cDR[d] * dist;
        nc = cc + cDC[d] * dist;
      } else {
        nr = rr + cKR[j - 56];
        nc = cc + cKC[j - 56];
      }
      val = (nr >= 0 && nr < 8 && nc >= 0 && nc < 8) ? Sl[f * 65 + nr * 8 + nc]
                                                     : NEG_INF;
    } else {
      if (f >= 48 && f < 56) continue;  // promo slots written from aup
      val = NEG_INF;
    }
    outb[idx] = val;
  }
}

extern "C" void kernel_launch(void* const* d_in, const int* in_sizes, int n_in,
                              void* d_out, int out_size, void* d_ws, size_t ws_size,
                              hipStream_t stream) {
  const float* x  = (const float*)d_in[0];
  const float* Wq = (const float*)d_in[1];
  const float* bq = (const float*)d_in[2];
  const float* Wk = (const float*)d_in[3];
  const float* bk = (const float*)d_in[4];
  const float* Wu = (const float*)d_in[5];
  const float* bu = (const float*)d_in[6];
  float* out = (float*)d_out;
  ushort* Wsw = (ushort*)d_ws;  // 16*18432 bf16 = 576 KB

  const int B = in_sizes[0] / 65536;

  wconv_kernel<<<288, 256, 0, stream>>>(Wq, Wk, Wu, Wsw);
  apol_main<<<B, 512, 0, stream>>>(x, bq, bk, bu, Wsw, out);
}